// Round 3
// baseline (774.930 us; speedup 1.0000x reference)
//
#include <hip/hip_runtime.h>
#include <hip/hip_bf16.h>

#define NTOK 8192
#define DIM 1024
#define HID 2816
#define NE 8
#define NSLOT (NTOK*2)
#define MAXMT1 (NSLOT/256 + NE)   // 72 worst-case M-tiles @ BM=256
#define MAXMT2 (NSLOT/128 + NE)   // 136 @ BM=128

typedef float f32x4 __attribute__((ext_vector_type(4)));
typedef __bf16 bf16x8 __attribute__((ext_vector_type(8)));
typedef __bf16 bf16x4 __attribute__((ext_vector_type(4)));

#define MFMA(a,b,c) __builtin_amdgcn_mfma_f32_16x16x32_bf16(a,b,c,0,0,0)
// element index in a [rows][32] bf16 half-block, XOR bank swizzle (R2-proven, 0 conflicts)
#define SWZ(r,g) (((r)<<5) + ((((g) ^ (((r)>>1)&3)))<<3))
#define VMW(N) asm volatile("s_waitcnt vmcnt(" #N ")" ::: "memory")
#define NOP do{}while(0)

__device__ __forceinline__ void cvt_st8(__bf16* d, f32x4 a, f32x4 b){
  bf16x8 v;
  v[0]=(__bf16)a.x; v[1]=(__bf16)a.y; v[2]=(__bf16)a.z; v[3]=(__bf16)a.w;
  v[4]=(__bf16)b.x; v[5]=(__bf16)b.y; v[6]=(__bf16)b.z; v[7]=(__bf16)b.w;
  *reinterpret_cast<bf16x8*>(d) = v;
}
__device__ __forceinline__ void gld_lds16(const void* g, void* l){
  __builtin_amdgcn_global_load_lds(
    (const __attribute__((address_space(1))) void*)g,
    (__attribute__((address_space(3))) void*)l, 16, 0, 0);
}
__device__ __forceinline__ int xcd_map(int orig, int nwg){
  int q = nwg>>3, rr = nwg&7, x = orig&7, o = orig>>3;
  return (x<rr ? x*(q+1) : rr*(q+1)+(x-rr)*q) + o;
}

// ---------------- small kernels ----------------
__global__ void k_zero(int* cnt){ if(threadIdx.x < NE) cnt[threadIdx.x] = 0; }

__global__ __launch_bounds__(256) void k_cvt(const float* __restrict__ src,
                                             __bf16* __restrict__ dst){
  int i = blockIdx.x*256 + threadIdx.x;
  const f32x4* s = reinterpret_cast<const f32x4*>(src) + (size_t)i*2;
  f32x4 a = s[0], b = s[1];
  cvt_st8(dst + (size_t)i*8, a, b);
}

__global__ __launch_bounds__(256) void k_gate(const float* __restrict__ x,
    const float* __restrict__ gw, int* __restrict__ idxs,
    float* __restrict__ wt, int* __restrict__ cnt, __bf16* __restrict__ xb)
{
  int lane = threadIdx.x & 63;
  int t = blockIdx.x*4 + (threadIdx.x >> 6);
  const f32x4* x4 = reinterpret_cast<const f32x4*>(x) + (size_t)t*(DIM/4);
  const f32x4* g4 = reinterpret_cast<const f32x4*>(gw);
  f32x4 xv[4];
#pragma unroll
  for(int i=0;i<4;i++) xv[i] = x4[i*64 + lane];
  double logit[NE];
#pragma unroll
  for(int e=0;e<NE;e++){
    double s = 0.0;
#pragma unroll
    for(int i=0;i<4;i++){
      f32x4 g = g4[e*(DIM/4) + i*64 + lane];
      s += (double)xv[i].x*g.x + (double)xv[i].y*g.y
         + (double)xv[i].z*g.z + (double)xv[i].w*g.w;
    }
#pragma unroll
    for(int d=32; d>0; d>>=1) s += __shfl_xor(s, d, 64);
    logit[e] = s;
  }
  __bf16* xo = xb + (size_t)t*DIM;
#pragma unroll
  for(int i=0;i<4;i++){
    bf16x4 v;
    v[0]=(__bf16)xv[i].x; v[1]=(__bf16)xv[i].y;
    v[2]=(__bf16)xv[i].z; v[3]=(__bf16)xv[i].w;
    *reinterpret_cast<bf16x4*>(xo + (i*64+lane)*4) = v;
  }
  if(lane==0){
    int i1=0; double m1=logit[0];
#pragma unroll
    for(int e=1;e<NE;e++) if(logit[e]>m1){ m1=logit[e]; i1=e; }
    int i2=-1; double m2=-1e300;
#pragma unroll
    for(int e=0;e<NE;e++) if(e!=i1 && logit[e]>m2){ m2=logit[e]; i2=e; }
    float e2 = __expf((float)(m2-m1));
    float w0 = 1.f/(1.f+e2);
    idxs[2*t]=i1; idxs[2*t+1]=i2;
    wt[2*t]=w0;   wt[2*t+1]=e2*w0;
    atomicAdd(&cnt[i1],1); atomicAdd(&cnt[i2],1);
  }
}

__global__ void k_prep(const int* __restrict__ cnt, int* __restrict__ off,
                       int* __restrict__ mtp1, int* __restrict__ mtp2,
                       int* __restrict__ cursor)
{
  if(threadIdx.x==0){
    int o=0, m1=0, m2=0; off[0]=0; mtp1[0]=0; mtp2[0]=0;
    for(int e=0;e<NE;e++){
      cursor[e]=o; o += cnt[e]; off[e+1]=o;
      m1 += (cnt[e]+255)>>8;  mtp1[e+1]=m1;
      m2 += (cnt[e]+127)>>7;  mtp2[e+1]=m2;
    }
  }
}

__global__ __launch_bounds__(256) void k_scatter(const int* __restrict__ idxs,
    int* __restrict__ cursor, int* __restrict__ order, int* __restrict__ inv)
{
  int t = blockIdx.x*blockDim.x + threadIdx.x;
#pragma unroll
  for(int k=0;k<2;k++){
    int s = 2*t+k;
    int e = idxs[s];
    int p = atomicAdd(&cursor[e],1);
    order[p]=s; inv[s]=p;
  }
}

// ======== FFN1: h = silu(x@w1^T) * (x@w3^T)  — 512thr, 256x128, BK=64, 8-phase ========
__global__ __launch_bounds__(512) void k_ffn1(
    const __bf16* __restrict__ xb, const __bf16* __restrict__ w1b,
    const __bf16* __restrict__ w3b, const int* __restrict__ off,
    const int* __restrict__ mtp1, const int* __restrict__ order,
    __bf16* __restrict__ h)
{
  __shared__ __align__(16) __bf16 sA [2][2][256*32];
  __shared__ __align__(16) __bf16 sB1[2][2][128*32];
  __shared__ __align__(16) __bf16 sB3[2][2][128*32];

  const int NT = HID/128;                // 22
  int wg = xcd_map(blockIdx.x, MAXMT1*NT);
  int mt = wg / NT, nt = wg % NT;
  if (mt >= mtp1[NE]) return;
  int e = 0;
  while (mt >= mtp1[e+1]) e++;
  int row0    = off[e] + (mt - mtp1[e])*256;
  int row_end = off[e+1];
  int n0      = nt*128;

  int tid = threadIdx.x, lane = tid&63, wave = tid>>6;
  int wm = wave>>2, wn = wave&3;         // 2x4 wave grid; wave tile 128x32
  int fr = lane&15, gq = lane>>4;
  int sr = tid>>2, gloc = tid&3;
  int swo = ((gloc ^ ((sr>>1)&3))<<3);   // pre-swizzled source granule offset

  int ar0 = min(row0 + sr,       row_end-1);
  int ar1 = min(row0 + sr + 128, row_end-1);
  const __bf16* a0  = xb  + (size_t)(order[ar0]>>1)*DIM + swo;
  const __bf16* a1  = xb  + (size_t)(order[ar1]>>1)*DIM + swo;
  const __bf16* b1p = w1b + (size_t)e*HID*DIM + (size_t)(n0+sr)*DIM + swo;
  const __bf16* b3p = w3b + (size_t)e*HID*DIM + (size_t)(n0+sr)*DIM + swo;

  f32x4 acc1[8][2], acc3[8][2];
#pragma unroll
  for(int m=0;m<8;m++)
#pragma unroll
    for(int n=0;n<2;n++){ acc1[m][n]=f32x4{0.f,0.f,0.f,0.f}; acc3[m][n]=f32x4{0.f,0.f,0.f,0.f}; }

#define F1_STGA(b, kt_, kk) { \
    gld_lds16(a0 + (kt_)*64 + (kk)*32, &sA[b][kk][wave<<9]); \
    gld_lds16(a1 + (kt_)*64 + (kk)*32, &sA[b][kk][4096 + (wave<<9)]); }
#define F1_STGB(b, kt_, kk) { \
    gld_lds16(b1p + (kt_)*64 + (kk)*32, &sB1[b][kk][wave<<9]); \
    gld_lds16(b3p + (kt_)*64 + (kk)*32, &sB3[b][kk][wave<<9]); }
#define F1_PH(b, kk, hh, RB, STAGE, WAITC) { \
    bf16x8 av[4]; \
    _Pragma("unroll") for(int m_=0;m_<4;m_++) \
      av[m_] = *(const bf16x8*)&sA[b][kk][SWZ(wm*128 + ((hh)*4+m_)*16 + fr, gq)]; \
    if(RB){ _Pragma("unroll") for(int n_=0;n_<2;n_++){ \
      bv1[n_] = *(const bf16x8*)&sB1[b][kk][SWZ(wn*32 + n_*16 + fr, gq)]; \
      bv3[n_] = *(const bf16x8*)&sB3[b][kk][SWZ(wn*32 + n_*16 + fr, gq)]; } } \
    STAGE; \
    __builtin_amdgcn_s_barrier(); \
    asm volatile("s_waitcnt lgkmcnt(0)" ::: "memory"); \
    __builtin_amdgcn_sched_barrier(0); \
    __builtin_amdgcn_s_setprio(1); \
    _Pragma("unroll") for(int m_=0;m_<4;m_++) _Pragma("unroll") for(int n_=0;n_<2;n_++){ \
      acc1[(hh)*4+m_][n_] = MFMA(av[m_], bv1[n_], acc1[(hh)*4+m_][n_]); \
      acc3[(hh)*4+m_][n_] = MFMA(av[m_], bv3[n_], acc3[(hh)*4+m_][n_]); } \
    __builtin_amdgcn_s_setprio(0); \
    WAITC; \
    __builtin_amdgcn_s_barrier(); }

  // prologue: tile0 fully + tile1.k0  (12 loads; retire tile0 -> vmcnt(4))
  F1_STGA(0,0,0); F1_STGB(0,0,0); F1_STGA(0,0,1); F1_STGB(0,0,1);
  F1_STGA(1,1,0); F1_STGB(1,1,0);
  VMW(4);
  __builtin_amdgcn_s_barrier();

  bf16x8 bv1[2], bv3[2];
  int kt = 0;
  const int NI = (DIM/64)/2;             // 8 iterations (16 K-tiles)
  for(int it=0; it<NI-1; ++it, kt+=2){
    F1_PH(0,0,0, 1, F1_STGA(1,kt+1,1), NOP);
    F1_PH(0,0,1, 0, F1_STGB(1,kt+1,1), NOP);
    F1_PH(0,1,0, 1, F1_STGA(0,kt+2,0), NOP);
    F1_PH(0,1,1, 0, F1_STGB(0,kt+2,0), VMW(4));
    F1_PH(1,0,0, 1, F1_STGA(0,kt+2,1), NOP);
    F1_PH(1,0,1, 0, F1_STGB(0,kt+2,1), NOP);
    F1_PH(1,1,0, 1, F1_STGA(1,kt+3,0), NOP);
    F1_PH(1,1,1, 0, F1_STGB(1,kt+3,0), VMW(4));
  }
  // peeled last iteration (kt = 14): only O.k1 staged; drain at ph4
  F1_PH(0,0,0, 1, F1_STGA(1,kt+1,1), NOP);
  F1_PH(0,0,1, 0, F1_STGB(1,kt+1,1), NOP);
  F1_PH(0,1,0, 1, NOP, NOP);
  F1_PH(0,1,1, 0, NOP, VMW(0));
  F1_PH(1,0,0, 1, NOP, NOP);
  F1_PH(1,0,1, 0, NOP, NOP);
  F1_PH(1,1,0, 1, NOP, NOP);
  F1_PH(1,1,1, 0, NOP, NOP);

  // epilogue: h = silu(acc1)*acc3, masked at segment end
#pragma unroll
  for(int m=0;m<8;m++){
    int rbase = row0 + wm*128 + m*16 + (gq<<2);
#pragma unroll
    for(int r=0;r<4;r++){
      if(rbase+r < row_end){
        __bf16* hp = h + (size_t)(rbase+r)*HID + n0 + wn*32 + fr;
#pragma unroll
        for(int n=0;n<2;n++){
          float u = acc1[m][n][r], v = acc3[m][n][r];
          hp[n*16] = (__bf16)( (u/(1.f+__expf(-u))) * v );
        }
      }
    }
  }
#undef F1_STGA
#undef F1_STGB
#undef F1_PH
}

// ======== FFN2: ys = h @ w2^T  — 256thr, 128x128, BK=64, 4-phase, 2 blk/CU ========
__global__ __launch_bounds__(256) void k_ffn2(
    const __bf16* __restrict__ h, const __bf16* __restrict__ w2b,
    const int* __restrict__ off, const int* __restrict__ mtp2,
    __bf16* __restrict__ ys)
{
  __shared__ __align__(16) __bf16 sA[2][2][128*32];
  __shared__ __align__(16) __bf16 sB[2][2][128*32];

  const int NT = DIM/128;                // 8
  int wg = xcd_map(blockIdx.x, MAXMT2*NT);
  int mt = wg / NT, nt = wg % NT;
  if (mt >= mtp2[NE]) return;
  int e = 0;
  while (mt >= mtp2[e+1]) e++;
  int row0    = off[e] + (mt - mtp2[e])*128;
  int row_end = off[e+1];
  int n0      = nt*128;

  int tid = threadIdx.x, lane = tid&63, wave = tid>>6;
  int wm = wave>>1, wn = wave&1;         // 2x2 wave grid; wave tile 64x64
  int fr = lane&15, gq = lane>>4;
  int sr = tid>>2, gloc = tid&3;         // sr in 0..63
  int swo = ((gloc ^ ((sr>>1)&3))<<3);

  int ar0 = min(row0 + sr,      NSLOT-1);
  int ar1 = min(row0 + sr + 64, NSLOT-1);
  const __bf16* a0 = h   + (size_t)ar0*HID + swo;
  const __bf16* a1 = h   + (size_t)ar1*HID + swo;
  const __bf16* b0 = w2b + (size_t)e*DIM*HID + (size_t)(n0+sr)*HID + swo;
  const __bf16* b1 = w2b + (size_t)e*DIM*HID + (size_t)(n0+sr+64)*HID + swo;

  f32x4 acc[4][4];
#pragma unroll
  for(int m=0;m<4;m++)
#pragma unroll
    for(int n=0;n<4;n++) acc[m][n]=f32x4{0.f,0.f,0.f,0.f};

#define F2_STGA(b, kt_, kk) { \
    gld_lds16(a0 + (kt_)*64 + (kk)*32, &sA[b][kk][wave<<9]); \
    gld_lds16(a1 + (kt_)*64 + (kk)*32, &sA[b][kk][2048 + (wave<<9)]); }
#define F2_STGB(b, kt_, kk) { \
    gld_lds16(b0 + (kt_)*64 + (kk)*32, &sB[b][kk][wave<<9]); \
    gld_lds16(b1 + (kt_)*64 + (kk)*32, &sB[b][kk][2048 + (wave<<9)]); }
#define F2_PH(b, kk, STAGE, WAITC) { \
    bf16x8 av[4], bv[4]; \
    _Pragma("unroll") for(int m_=0;m_<4;m_++) \
      av[m_] = *(const bf16x8*)&sA[b][kk][SWZ(wm*64 + m_*16 + fr, gq)]; \
    _Pragma("unroll") for(int n_=0;n_<4;n_++) \
      bv[n_] = *(const bf16x8*)&sB[b][kk][SWZ(wn*64 + n_*16 + fr, gq)]; \
    STAGE; \
    __builtin_amdgcn_s_barrier(); \
    asm volatile("s_waitcnt lgkmcnt(0)" ::: "memory"); \
    __builtin_amdgcn_sched_barrier(0); \
    __builtin_amdgcn_s_setprio(1); \
    _Pragma("unroll") for(int m_=0;m_<4;m_++) _Pragma("unroll") for(int n_=0;n_<4;n_++) \
      acc[m_][n_] = MFMA(av[m_], bv[n_], acc[m_][n_]); \
    __builtin_amdgcn_s_setprio(0); \
    WAITC; \
    __builtin_amdgcn_s_barrier(); }

  // prologue: tile0 fully + tile1.k0 (12 loads; retire tile0)
  F2_STGA(0,0,0); F2_STGB(0,0,0); F2_STGA(0,0,1); F2_STGB(0,0,1);
  F2_STGA(1,1,0); F2_STGB(1,1,0);
  VMW(4);
  __builtin_amdgcn_s_barrier();

  int kt = 0;
  const int NI = (HID/64)/2;             // 22 iterations (44 K-tiles)
  for(int it=0; it<NI-1; ++it, kt+=2){
    F2_PH(0,0, { F2_STGA(1,kt+1,1); F2_STGB(1,kt+1,1); }, NOP);
    F2_PH(0,1, { F2_STGA(0,kt+2,0); F2_STGB(0,kt+2,0); }, VMW(4));
    F2_PH(1,0, { F2_STGA(0,kt+2,1); F2_STGB(0,kt+2,1); }, NOP);
    F2_PH(1,1, { F2_STGA(1,kt+3,0); F2_STGB(1,kt+3,0); }, VMW(4));
  }
  // peel (kt = 42)
  F2_PH(0,0, { F2_STGA(1,kt+1,1); F2_STGB(1,kt+1,1); }, NOP);
  F2_PH(0,1, NOP, VMW(0));
  F2_PH(1,0, NOP, NOP);
  F2_PH(1,1, NOP, NOP);

  // epilogue: per-slot bf16 ys (no atomics; combine gathers later)
#pragma unroll
  for(int m=0;m<4;m++){
    int rbase = row0 + wm*64 + m*16 + (gq<<2);
#pragma unroll
    for(int r=0;r<4;r++){
      if(rbase+r < row_end){
        __bf16* yp = ys + (size_t)(rbase+r)*DIM + n0 + wn*64 + fr;
#pragma unroll
        for(int n=0;n<4;n++) yp[n*16] = (__bf16)acc[m][n][r];
      }
    }
  }
#undef F2_STGA
#undef F2_STGB
#undef F2_PH
}

// ---------------- weighted combine ----------------
__global__ __launch_bounds__(256) void k_combine(
    const __bf16* __restrict__ ys, const int* __restrict__ inv,
    const float* __restrict__ wt, float* __restrict__ y)
{
  int t  = blockIdx.x;
  int p0 = inv[2*t], p1 = inv[2*t+1];
  float w0 = wt[2*t], w1v = wt[2*t+1];
  int d = threadIdx.x*4;
  const __bf16* r0 = ys + (size_t)p0*DIM + d;
  const __bf16* r1 = ys + (size_t)p1*DIM + d;
  f32x4 o;
#pragma unroll
  for(int j=0;j<4;j++) o[j] = w0*(float)r0[j] + w1v*(float)r1[j];
  *reinterpret_cast<f32x4*>(y + (size_t)t*DIM + d) = o;
}

// ---------------- launch ----------------
extern "C" void kernel_launch(void* const* d_in, const int* in_sizes, int n_in,
                              void* d_out, int out_size, void* d_ws, size_t ws_size,
                              hipStream_t stream)
{
  const float* x  = (const float*)d_in[0];
  const float* gw = (const float*)d_in[1];
  const float* w1 = (const float*)d_in[2];
  const float* w3 = (const float*)d_in[3];
  const float* w2 = (const float*)d_in[4];
  float* y = (float*)d_out;
  char* ws = (char*)d_ws;

  int*   cnt    = (int*)(ws + 0);
  int*   off    = (int*)(ws + 64);
  int*   mtp1   = (int*)(ws + 128);
  int*   mtp2   = (int*)(ws + 192);
  int*   cursor = (int*)(ws + 256);
  int*   idxs   = (int*)(ws + 320);
  float* wt     = (float*)(ws + 320 + 65536);
  int*   order  = (int*)(ws + 320 + 2*65536);
  int*   inv    = (int*)(ws + 320 + 3*65536);
  __bf16* h     = (__bf16*)(ws + 262464);
  __bf16* xb    = (__bf16*)(ws + 262464 + 92274688ull);
  __bf16* w1b   = (__bf16*)(ws + 262464 + 92274688ull + 16777216ull);
  __bf16* w3b   = (__bf16*)(ws + 262464 + 92274688ull + 16777216ull + 46137344ull);
  __bf16* w2b   = (__bf16*)(ws + 262464 + 92274688ull + 16777216ull + 2*46137344ull);
  __bf16* ysb   = w1b;   // dead after k_ffn1 -> reuse (33.5MB <= 46MB)

  const int WN8 = NE*HID*DIM/8;

  k_zero   <<<1, 64, 0, stream>>>(cnt);
  k_gate   <<<NTOK/4, 256, 0, stream>>>(x, gw, idxs, wt, cnt, xb);
  k_prep   <<<1, 64, 0, stream>>>(cnt, off, mtp1, mtp2, cursor);
  k_scatter<<<NTOK/256, 256, 0, stream>>>(idxs, cursor, order, inv);
  k_cvt    <<<WN8/256, 256, 0, stream>>>(w1, w1b);
  k_cvt    <<<WN8/256, 256, 0, stream>>>(w3, w3b);
  k_cvt    <<<WN8/256, 256, 0, stream>>>(w2, w2b);
  k_ffn1   <<<MAXMT1*(HID/128), 512, 0, stream>>>(xb, w1b, w3b, off, mtp1, order, h);
  k_ffn2   <<<MAXMT2*(DIM/128), 256, 0, stream>>>(h, w2b, off, mtp2, ysb);
  k_combine<<<NTOK, 256, 0, stream>>>(ysb, inv, wt, y);
}

// Round 4
// 746.756 us; speedup vs baseline: 1.0377x; 1.0377x over previous
//
#include <hip/hip_runtime.h>
#include <hip/hip_bf16.h>

#define NTOK 8192
#define DIM 1024
#define HID 2816
#define NE 8
#define NSLOT (NTOK*2)
#define MAXMT1 (NSLOT/256 + NE)   // 72 worst-case M-tiles @ BM=256
#define MAXMT2 (NSLOT/128 + NE)   // 136 @ BM=128

typedef float f32x4 __attribute__((ext_vector_type(4)));
typedef __bf16 bf16x8 __attribute__((ext_vector_type(8)));
typedef __bf16 bf16x4 __attribute__((ext_vector_type(4)));

#define MFMA(a,b,c) __builtin_amdgcn_mfma_f32_16x16x32_bf16(a,b,c,0,0,0)
// element index in a [rows][32] bf16 half-block, XOR bank swizzle (R2-proven, 0 conflicts)
#define SWZ(r,g) (((r)<<5) + ((((g) ^ (((r)>>1)&3)))<<3))
#define VMW(N) asm volatile("s_waitcnt vmcnt(" #N ")" ::: "memory")
#define NOP do{}while(0)

__device__ __forceinline__ void cvt_st8(__bf16* d, f32x4 a, f32x4 b){
  bf16x8 v;
  v[0]=(__bf16)a.x; v[1]=(__bf16)a.y; v[2]=(__bf16)a.z; v[3]=(__bf16)a.w;
  v[4]=(__bf16)b.x; v[5]=(__bf16)b.y; v[6]=(__bf16)b.z; v[7]=(__bf16)b.w;
  *reinterpret_cast<bf16x8*>(d) = v;
}
__device__ __forceinline__ void gld_lds16(const void* g, void* l){
  __builtin_amdgcn_global_load_lds(
    (const __attribute__((address_space(1))) void*)g,
    (__attribute__((address_space(3))) void*)l, 16, 0, 0);
}
__device__ __forceinline__ int xcd_map(int orig, int nwg){
  int q = nwg>>3, rr = nwg&7, x = orig&7, o = orig>>3;
  return (x<rr ? x*(q+1) : rr*(q+1)+(x-rr)*q) + o;
}

// ---------------- small kernels ----------------
__global__ void k_zero(int* cnt){ if(threadIdx.x < NE) cnt[threadIdx.x] = 0; }

__global__ __launch_bounds__(256) void k_cvt(const float* __restrict__ src,
                                             __bf16* __restrict__ dst){
  int i = blockIdx.x*256 + threadIdx.x;
  const f32x4* s = reinterpret_cast<const f32x4*>(src) + (size_t)i*2;
  f32x4 a = s[0], b = s[1];
  cvt_st8(dst + (size_t)i*8, a, b);
}

__global__ __launch_bounds__(256) void k_gate(const float* __restrict__ x,
    const float* __restrict__ gw, int* __restrict__ idxs,
    float* __restrict__ wt, int* __restrict__ cnt, __bf16* __restrict__ xb)
{
  int lane = threadIdx.x & 63;
  int t = blockIdx.x*4 + (threadIdx.x >> 6);
  const f32x4* x4 = reinterpret_cast<const f32x4*>(x) + (size_t)t*(DIM/4);
  const f32x4* g4 = reinterpret_cast<const f32x4*>(gw);
  f32x4 xv[4];
#pragma unroll
  for(int i=0;i<4;i++) xv[i] = x4[i*64 + lane];
  double logit[NE];
#pragma unroll
  for(int e=0;e<NE;e++){
    double s = 0.0;
#pragma unroll
    for(int i=0;i<4;i++){
      f32x4 g = g4[e*(DIM/4) + i*64 + lane];
      s += (double)xv[i].x*g.x + (double)xv[i].y*g.y
         + (double)xv[i].z*g.z + (double)xv[i].w*g.w;
    }
#pragma unroll
    for(int d=32; d>0; d>>=1) s += __shfl_xor(s, d, 64);
    logit[e] = s;
  }
  __bf16* xo = xb + (size_t)t*DIM;
#pragma unroll
  for(int i=0;i<4;i++){
    bf16x4 v;
    v[0]=(__bf16)xv[i].x; v[1]=(__bf16)xv[i].y;
    v[2]=(__bf16)xv[i].z; v[3]=(__bf16)xv[i].w;
    *reinterpret_cast<bf16x4*>(xo + (i*64+lane)*4) = v;
  }
  if(lane==0){
    int i1=0; double m1=logit[0];
#pragma unroll
    for(int e=1;e<NE;e++) if(logit[e]>m1){ m1=logit[e]; i1=e; }
    int i2=-1; double m2=-1e300;
#pragma unroll
    for(int e=0;e<NE;e++) if(e!=i1 && logit[e]>m2){ m2=logit[e]; i2=e; }
    float e2 = __expf((float)(m2-m1));
    float w0 = 1.f/(1.f+e2);
    idxs[2*t]=i1; idxs[2*t+1]=i2;
    wt[2*t]=w0;   wt[2*t+1]=e2*w0;
    atomicAdd(&cnt[i1],1); atomicAdd(&cnt[i2],1);
  }
}

__global__ void k_prep(const int* __restrict__ cnt, int* __restrict__ off,
                       int* __restrict__ mtp1, int* __restrict__ mtp2,
                       int* __restrict__ cursor)
{
  if(threadIdx.x==0){
    int o=0, m1=0, m2=0; off[0]=0; mtp1[0]=0; mtp2[0]=0;
    for(int e=0;e<NE;e++){
      cursor[e]=o; o += cnt[e]; off[e+1]=o;
      m1 += (cnt[e]+255)>>8;  mtp1[e+1]=m1;
      m2 += (cnt[e]+127)>>7;  mtp2[e+1]=m2;
    }
  }
}

__global__ __launch_bounds__(256) void k_scatter(const int* __restrict__ idxs,
    int* __restrict__ cursor, int* __restrict__ order, int* __restrict__ inv)
{
  int t = blockIdx.x*blockDim.x + threadIdx.x;
#pragma unroll
  for(int k=0;k<2;k++){
    int s = 2*t+k;
    int e = idxs[s];
    int p = atomicAdd(&cursor[e],1);
    order[p]=s; inv[s]=p;
  }
}

// ======== FFN1: 8-phase with DERIVED waits (VMW(8) every even phase) ========
__global__ __launch_bounds__(512) void k_ffn1(
    const __bf16* __restrict__ xb, const __bf16* __restrict__ w1b,
    const __bf16* __restrict__ w3b, const int* __restrict__ off,
    const int* __restrict__ mtp1, const int* __restrict__ order,
    __bf16* __restrict__ h)
{
  __shared__ __align__(16) __bf16 sA [2][2][256*32];
  __shared__ __align__(16) __bf16 sB1[2][2][128*32];
  __shared__ __align__(16) __bf16 sB3[2][2][128*32];

  const int NT = HID/128;                // 22
  int wg = xcd_map(blockIdx.x, MAXMT1*NT);
  int mt = wg / NT, nt = wg % NT;
  if (mt >= mtp1[NE]) return;
  int e = 0;
  while (mt >= mtp1[e+1]) e++;
  int row0    = off[e] + (mt - mtp1[e])*256;
  int row_end = off[e+1];
  int n0      = nt*128;

  int tid = threadIdx.x, lane = tid&63, wave = tid>>6;
  int wm = wave>>2, wn = wave&3;         // 2x4 wave grid; wave tile 128x32 (x2 tensors)
  int fr = lane&15, gq = lane>>4;
  int sr = tid>>2, gloc = tid&3;
  int swo = ((gloc ^ ((sr>>1)&3))<<3);   // pre-swizzled source granule offset

  int ar0 = min(row0 + sr,       row_end-1);
  int ar1 = min(row0 + sr + 128, row_end-1);
  const __bf16* a0  = xb  + (size_t)(order[ar0]>>1)*DIM + swo;
  const __bf16* a1  = xb  + (size_t)(order[ar1]>>1)*DIM + swo;
  const __bf16* b1p = w1b + (size_t)e*HID*DIM + (size_t)(n0+sr)*DIM + swo;
  const __bf16* b3p = w3b + (size_t)e*HID*DIM + (size_t)(n0+sr)*DIM + swo;

  f32x4 acc1[8][2], acc3[8][2];
#pragma unroll
  for(int m=0;m<8;m++)
#pragma unroll
    for(int n=0;n<2;n++){ acc1[m][n]=f32x4{0.f,0.f,0.f,0.f}; acc3[m][n]=f32x4{0.f,0.f,0.f,0.f}; }

#define F1_STGA(b, kt_, kk) { \
    gld_lds16(a0 + (kt_)*64 + (kk)*32, &sA[b][kk][wave<<9]); \
    gld_lds16(a1 + (kt_)*64 + (kk)*32, &sA[b][kk][4096 + (wave<<9)]); }
#define F1_STGB(b, kt_, kk) { \
    gld_lds16(b1p + (kt_)*64 + (kk)*32, &sB1[b][kk][wave<<9]); \
    gld_lds16(b3p + (kt_)*64 + (kk)*32, &sB3[b][kk][wave<<9]); }
#define F1_PH(b, kk, hh, RB, STAGE, WAITC) { \
    bf16x8 av[4]; \
    _Pragma("unroll") for(int m_=0;m_<4;m_++) \
      av[m_] = *(const bf16x8*)&sA[b][kk][SWZ(wm*128 + ((hh)*4+m_)*16 + fr, gq)]; \
    if(RB){ _Pragma("unroll") for(int n_=0;n_<2;n_++){ \
      bv1[n_] = *(const bf16x8*)&sB1[b][kk][SWZ(wn*32 + n_*16 + fr, gq)]; \
      bv3[n_] = *(const bf16x8*)&sB3[b][kk][SWZ(wn*32 + n_*16 + fr, gq)]; } } \
    STAGE; \
    __builtin_amdgcn_s_barrier(); \
    asm volatile("s_waitcnt lgkmcnt(0)" ::: "memory"); \
    __builtin_amdgcn_sched_barrier(0); \
    __builtin_amdgcn_s_setprio(1); \
    _Pragma("unroll") for(int m_=0;m_<4;m_++) _Pragma("unroll") for(int n_=0;n_<2;n_++){ \
      acc1[(hh)*4+m_][n_] = MFMA(av[m_], bv1[n_], acc1[(hh)*4+m_][n_]); \
      acc3[(hh)*4+m_][n_] = MFMA(av[m_], bv3[n_], acc3[(hh)*4+m_][n_]); } \
    __builtin_amdgcn_s_setprio(0); \
    WAITC; \
    __builtin_amdgcn_s_barrier(); }

  // prologue: t0 both halves + t1.k0 (6 units, 12 loads); VMW(8) -> t0.k0 landed,
  // leaves 4 units in flight (t0.k1, t1.k0) = steady-state invariant.
  F1_STGA(0,0,0); F1_STGB(0,0,0); F1_STGA(0,0,1); F1_STGB(0,0,1);
  F1_STGA(1,1,0); F1_STGB(1,1,0);
  VMW(8);
  __builtin_amdgcn_s_barrier();

  bf16x8 bv1[2], bv3[2];
  int kt = 0;
  const int NI = (DIM/64)/2;             // 8 iterations (16 K-tiles)
  // Derived waits: VMW(8) at every even phase waits ONLY for the unit pair
  // issued 5-6 phases earlier (the half needed next odd phase). Never deeper.
  for(int it=0; it<NI-1; ++it, kt+=2){
    F1_PH(0,0,0, 1, F1_STGA(1,kt+1,1), NOP);
    F1_PH(0,0,1, 0, F1_STGB(1,kt+1,1), VMW(8));   // retires (buf0,k1): read ph3
    F1_PH(0,1,0, 1, F1_STGA(0,kt+2,0), NOP);
    F1_PH(0,1,1, 0, F1_STGB(0,kt+2,0), VMW(8));   // retires (buf1,k0): read ph5
    F1_PH(1,0,0, 1, F1_STGA(0,kt+2,1), NOP);
    F1_PH(1,0,1, 0, F1_STGB(0,kt+2,1), VMW(8));   // retires (buf1,k1): read ph7
    F1_PH(1,1,0, 1, F1_STGA(1,kt+3,0), NOP);
    F1_PH(1,1,1, 0, F1_STGB(1,kt+3,0), VMW(8));   // retires (buf0',k0): read ph1'
  }
  // peel (kt==14): stage only t15.k1
  F1_PH(0,0,0, 1, F1_STGA(1,kt+1,1), NOP);
  F1_PH(0,0,1, 0, F1_STGB(1,kt+1,1), VMW(8));     // retires t14.k1
  F1_PH(0,1,0, 1, NOP, NOP);
  F1_PH(0,1,1, 0, NOP, VMW(4));                   // retires t15.k0
  F1_PH(1,0,0, 1, NOP, NOP);
  F1_PH(1,0,1, 0, NOP, VMW(0));                   // retires t15.k1
  F1_PH(1,1,0, 1, NOP, NOP);
  F1_PH(1,1,1, 0, NOP, NOP);

  // epilogue: h = silu(acc1)*acc3, masked at segment end
#pragma unroll
  for(int m=0;m<8;m++){
    int rbase = row0 + wm*128 + m*16 + (gq<<2);
#pragma unroll
    for(int r=0;r<4;r++){
      if(rbase+r < row_end){
        __bf16* hp = h + (size_t)(rbase+r)*HID + n0 + wn*32 + fr;
#pragma unroll
        for(int n=0;n<2;n++){
          float u = acc1[m][n][r], v = acc3[m][n][r];
          hp[n*16] = (__bf16)( (u/(1.f+__expf(-u))) * v );
        }
      }
    }
  }
#undef F1_STGA
#undef F1_STGB
#undef F1_PH
}

// ======== FFN2: R2-proven 2-phase, 512thr, 128x128, BK=32, ys epilogue ========
__global__ __launch_bounds__(512) void k_ffn2(
    const __bf16* __restrict__ h, const __bf16* __restrict__ w2b,
    const int* __restrict__ off, const int* __restrict__ mtp2,
    __bf16* __restrict__ ys)
{
  __shared__ __align__(16) __bf16 lA[2][128*32];
  __shared__ __align__(16) __bf16 lB[2][128*32];

  const int NT = DIM/128;                // 8
  int wg = xcd_map(blockIdx.x, MAXMT2*NT);
  int mt = wg / NT, nt = wg % NT;
  if (mt >= mtp2[NE]) return;
  int e = 0;
  while (mt >= mtp2[e+1]) e++;
  int row0    = off[e] + (mt - mtp2[e])*128;
  int row_end = off[e+1];
  int n0      = nt*128;

  int tid = threadIdx.x, lane = tid&63;
  int srow = tid>>2;
  int scol = ((tid&3) ^ ((srow>>1)&3))<<3;
  int hrow = min(row0 + srow, NSLOT-1);
  const __bf16* gA = h   + (size_t)hrow*HID + scol;
  const __bf16* gB = w2b + (size_t)e*DIM*HID + (size_t)(n0+srow)*HID + scol;
  int ldso = (tid>>6)<<9;

  int wm = (tid>>6)>>2, wn = (tid>>6)&3;
  int fr = lane & 15, gq = lane>>4;

  f32x4 acc[4][2];
#pragma unroll
  for(int m=0;m<4;m++)
#pragma unroll
    for(int n=0;n<2;n++) acc[m][n]=f32x4{0.f,0.f,0.f,0.f};

  gld_lds16(gA, &lA[0][ldso]);
  gld_lds16(gB, &lB[0][ldso]);
  __syncthreads();

  const int NK = HID/32;                 // 88
  int buf=0;
  for(int kt=0; kt<NK; kt++){
    if(kt+1<NK){
      gld_lds16(gA + (kt+1)*32, &lA[buf^1][ldso]);
      gld_lds16(gB + (kt+1)*32, &lB[buf^1][ldso]);
    }
    bf16x8 av[4], bv[2];
#pragma unroll
    for(int m=0;m<4;m++) av[m]=*reinterpret_cast<const bf16x8*>(&lA[buf][SWZ(wm*64+m*16+fr, gq)]);
#pragma unroll
    for(int n=0;n<2;n++) bv[n]=*reinterpret_cast<const bf16x8*>(&lB[buf][SWZ(wn*32+n*16+fr, gq)]);
#pragma unroll
    for(int m=0;m<4;m++)
#pragma unroll
      for(int n=0;n<2;n++)
        acc[m][n]=MFMA(av[m],bv[n],acc[m][n]);
    __syncthreads();
    buf^=1;
  }

  // epilogue: per-slot bf16 ys (no atomics)
#pragma unroll
  for(int m=0;m<4;m++){
    int rbase = row0 + wm*64 + m*16 + (gq<<2);
#pragma unroll
    for(int r=0;r<4;r++){
      if(rbase+r < row_end){
        __bf16* yp = ys + (size_t)(rbase+r)*DIM + n0 + wn*32 + fr;
        yp[0]  = (__bf16)acc[m][0][r];
        yp[16] = (__bf16)acc[m][1][r];
      }
    }
  }
}

// ---------------- weighted combine ----------------
__global__ __launch_bounds__(256) void k_combine(
    const __bf16* __restrict__ ys, const int* __restrict__ inv,
    const float* __restrict__ wt, float* __restrict__ y)
{
  int t  = blockIdx.x;
  int p0 = inv[2*t], p1 = inv[2*t+1];
  float w0 = wt[2*t], w1v = wt[2*t+1];
  int d = threadIdx.x*4;
  const __bf16* r0 = ys + (size_t)p0*DIM + d;
  const __bf16* r1 = ys + (size_t)p1*DIM + d;
  f32x4 o;
#pragma unroll
  for(int j=0;j<4;j++) o[j] = w0*(float)r0[j] + w1v*(float)r1[j];
  *reinterpret_cast<f32x4*>(y + (size_t)t*DIM + d) = o;
}

// ---------------- launch ----------------
extern "C" void kernel_launch(void* const* d_in, const int* in_sizes, int n_in,
                              void* d_out, int out_size, void* d_ws, size_t ws_size,
                              hipStream_t stream)
{
  const float* x  = (const float*)d_in[0];
  const float* gw = (const float*)d_in[1];
  const float* w1 = (const float*)d_in[2];
  const float* w3 = (const float*)d_in[3];
  const float* w2 = (const float*)d_in[4];
  float* y = (float*)d_out;
  char* ws = (char*)d_ws;

  int*   cnt    = (int*)(ws + 0);
  int*   off    = (int*)(ws + 64);
  int*   mtp1   = (int*)(ws + 128);
  int*   mtp2   = (int*)(ws + 192);
  int*   cursor = (int*)(ws + 256);
  int*   idxs   = (int*)(ws + 320);
  float* wt     = (float*)(ws + 320 + 65536);
  int*   order  = (int*)(ws + 320 + 2*65536);
  int*   inv    = (int*)(ws + 320 + 3*65536);
  __bf16* h     = (__bf16*)(ws + 262464);
  __bf16* xb    = (__bf16*)(ws + 262464 + 92274688ull);
  __bf16* w1b   = (__bf16*)(ws + 262464 + 92274688ull + 16777216ull);
  __bf16* w3b   = (__bf16*)(ws + 262464 + 92274688ull + 16777216ull + 46137344ull);
  __bf16* w2b   = (__bf16*)(ws + 262464 + 92274688ull + 16777216ull + 2*46137344ull);
  __bf16* ysb   = w1b;   // dead after k_ffn1 -> reuse (33.5MB <= 46MB)

  const int WN8 = NE*HID*DIM/8;

  k_zero   <<<1, 64, 0, stream>>>(cnt);
  k_gate   <<<NTOK/4, 256, 0, stream>>>(x, gw, idxs, wt, cnt, xb);
  k_prep   <<<1, 64, 0, stream>>>(cnt, off, mtp1, mtp2, cursor);
  k_scatter<<<NTOK/256, 256, 0, stream>>>(idxs, cursor, order, inv);
  k_cvt    <<<WN8/256, 256, 0, stream>>>(w1, w1b);
  k_cvt    <<<WN8/256, 256, 0, stream>>>(w3, w3b);
  k_cvt    <<<WN8/256, 256, 0, stream>>>(w2, w2b);
  k_ffn1   <<<MAXMT1*(HID/128), 512, 0, stream>>>(xb, w1b, w3b, off, mtp1, order, h);
  k_ffn2   <<<MAXMT2*(DIM/128), 512, 0, stream>>>(h, w2b, off, mtp2, ysb);
  k_combine<<<NTOK, 256, 0, stream>>>(ysb, inv, wt, y);
}

// Round 5
// 732.014 us; speedup vs baseline: 1.0586x; 1.0201x over previous
//
#include <hip/hip_runtime.h>
#include <hip/hip_bf16.h>

#define NTOK 8192
#define DIM 1024
#define HID 2816
#define NE 8
#define NSLOT (NTOK*2)
#define BM 128
#define BK 32
#define MAXMT (NSLOT/BM + NE)   // 136 worst-case M-tiles @ BM=128

typedef float f32x4 __attribute__((ext_vector_type(4)));
typedef __bf16 bf16x8 __attribute__((ext_vector_type(8)));
typedef __bf16 bf16x4 __attribute__((ext_vector_type(4)));

#define MFMA(a,b,c) __builtin_amdgcn_mfma_f32_16x16x32_bf16(a,b,c,0,0,0)
// element index in a linear [rows][32] bf16 tile, XOR bank swizzle (R2-proven: 0 conflicts)
#define SWZ(r,g) (((r)<<5) + ((((g) ^ (((r)>>1)&3)))<<3))

__device__ __forceinline__ void cvt_st8(__bf16* d, f32x4 a, f32x4 b){
  bf16x8 v;
  v[0]=(__bf16)a.x; v[1]=(__bf16)a.y; v[2]=(__bf16)a.z; v[3]=(__bf16)a.w;
  v[4]=(__bf16)b.x; v[5]=(__bf16)b.y; v[6]=(__bf16)b.z; v[7]=(__bf16)b.w;
  *reinterpret_cast<bf16x8*>(d) = v;
}
__device__ __forceinline__ void gld_lds16(const void* g, void* l){
  __builtin_amdgcn_global_load_lds(
    (const __attribute__((address_space(1))) void*)g,
    (__attribute__((address_space(3))) void*)l, 16, 0, 0);
}
__device__ __forceinline__ int xcd_map(int orig, int nwg){
  int q = nwg>>3, rr = nwg&7, x = orig&7, o = orig>>3;
  return (x<rr ? x*(q+1) : rr*(q+1)+(x-rr)*q) + o;
}

// ---------------- small kernels ----------------
__global__ void k_zero(int* cnt){ if(threadIdx.x < NE) cnt[threadIdx.x] = 0; }

// fused fp32->bf16 conversion for w1,w3,w2 (equal sizes)
__global__ __launch_bounds__(256) void k_cvt3(
    const float* __restrict__ s1, const float* __restrict__ s3,
    const float* __restrict__ s2, __bf16* __restrict__ d1,
    __bf16* __restrict__ d3, __bf16* __restrict__ d2)
{
  const int PB = (NE*HID*DIM/8)/256;     // 11264 blocks per tensor
  int seg = blockIdx.x / PB;
  int i   = (blockIdx.x % PB)*256 + threadIdx.x;
  const float* src = (seg==0) ? s1 : (seg==1) ? s3 : s2;
  __bf16*      dst = (seg==0) ? d1 : (seg==1) ? d3 : d2;
  const f32x4* s = reinterpret_cast<const f32x4*>(src) + (size_t)i*2;
  f32x4 a = s[0], b = s[1];
  cvt_st8(dst + (size_t)i*8, a, b);
}

__global__ __launch_bounds__(256) void k_gate(const float* __restrict__ x,
    const float* __restrict__ gw, int* __restrict__ idxs,
    float* __restrict__ wt, int* __restrict__ cnt, __bf16* __restrict__ xb)
{
  int lane = threadIdx.x & 63;
  int t = blockIdx.x*4 + (threadIdx.x >> 6);
  const f32x4* x4 = reinterpret_cast<const f32x4*>(x) + (size_t)t*(DIM/4);
  const f32x4* g4 = reinterpret_cast<const f32x4*>(gw);
  f32x4 xv[4];
#pragma unroll
  for(int i=0;i<4;i++) xv[i] = x4[i*64 + lane];
  double logit[NE];
#pragma unroll
  for(int e=0;e<NE;e++){
    double s = 0.0;
#pragma unroll
    for(int i=0;i<4;i++){
      f32x4 g = g4[e*(DIM/4) + i*64 + lane];
      s += (double)xv[i].x*g.x + (double)xv[i].y*g.y
         + (double)xv[i].z*g.z + (double)xv[i].w*g.w;
    }
#pragma unroll
    for(int d=32; d>0; d>>=1) s += __shfl_xor(s, d, 64);
    logit[e] = s;
  }
  __bf16* xo = xb + (size_t)t*DIM;
#pragma unroll
  for(int i=0;i<4;i++){
    bf16x4 v;
    v[0]=(__bf16)xv[i].x; v[1]=(__bf16)xv[i].y;
    v[2]=(__bf16)xv[i].z; v[3]=(__bf16)xv[i].w;
    *reinterpret_cast<bf16x4*>(xo + (i*64+lane)*4) = v;
  }
  if(lane==0){
    int i1=0; double m1=logit[0];
#pragma unroll
    for(int e=1;e<NE;e++) if(logit[e]>m1){ m1=logit[e]; i1=e; }
    int i2=-1; double m2=-1e300;
#pragma unroll
    for(int e=0;e<NE;e++) if(e!=i1 && logit[e]>m2){ m2=logit[e]; i2=e; }
    float e2 = __expf((float)(m2-m1));
    float w0 = 1.f/(1.f+e2);
    idxs[2*t]=i1; idxs[2*t+1]=i2;
    wt[2*t]=w0;   wt[2*t+1]=e2*w0;
    atomicAdd(&cnt[i1],1); atomicAdd(&cnt[i2],1);
  }
}

__global__ void k_prep(const int* __restrict__ cnt, int* __restrict__ off,
                       int* __restrict__ mtp, int* __restrict__ cursor)
{
  if(threadIdx.x==0){
    int o=0, m=0; off[0]=0; mtp[0]=0;
    for(int e=0;e<NE;e++){
      cursor[e]=o; o += cnt[e]; off[e+1]=o;
      m += (cnt[e]+BM-1)/BM;  mtp[e+1]=m;
    }
  }
}

__global__ __launch_bounds__(256) void k_scatter(const int* __restrict__ idxs,
    int* __restrict__ cursor, int* __restrict__ order, int* __restrict__ inv)
{
  int t = blockIdx.x*blockDim.x + threadIdx.x;
#pragma unroll
  for(int k=0;k<2;k++){
    int s = 2*t+k;
    int e = idxs[s];
    int p = atomicAdd(&cursor[e],1);
    order[p]=s; inv[s]=p;
  }
}

// ======== FFN1 (R2-proven): h = silu(x@w1^T)*(x@w3^T), 128x128x2, BK=32 ========
__global__ __launch_bounds__(512) void k_ffn1(
    const __bf16* __restrict__ xb, const __bf16* __restrict__ w1b,
    const __bf16* __restrict__ w3b, const int* __restrict__ off,
    const int* __restrict__ mtp, const int* __restrict__ order,
    __bf16* __restrict__ h)
{
  __shared__ __align__(16) __bf16 lA [2][BM*BK];
  __shared__ __align__(16) __bf16 lB1[2][BM*BK];
  __shared__ __align__(16) __bf16 lB3[2][BM*BK];

  const int NT = HID/128;                // 22
  int wg = xcd_map(blockIdx.x, MAXMT*NT);
  int mt = wg / NT, nt = wg % NT;
  if (mt >= mtp[NE]) return;
  int e = 0;
  while (mt >= mtp[e+1]) e++;
  int row0    = off[e] + (mt - mtp[e])*BM;
  int row_end = off[e+1];
  int n0      = nt*128;

  int tid = threadIdx.x, lane = tid&63;
  int srow = tid>>2;
  int scol = ((tid&3) ^ ((srow>>1)&3))<<3;   // pre-swizzled source granule
  int arow = min(row0 + srow, row_end-1);
  int tok  = order[arow] >> 1;
  const __bf16* gA  = xb  + (size_t)tok*DIM + scol;
  const __bf16* gB1 = w1b + (size_t)e*HID*DIM + (size_t)(n0+srow)*DIM + scol;
  const __bf16* gB3 = w3b + (size_t)e*HID*DIM + (size_t)(n0+srow)*DIM + scol;
  int ldso = (tid>>6)<<9;                // wave * 512 elements (1KB)

  int wm = (tid>>6)>>2, wn = (tid>>6)&3; // 2x4 wave grid, wave tile 64x32 (x2 tensors)
  int fr = lane & 15, gq = lane>>4;

  f32x4 acc1[4][2], acc3[4][2];
#pragma unroll
  for(int m=0;m<4;m++)
#pragma unroll
    for(int n=0;n<2;n++){ acc1[m][n]=f32x4{0.f,0.f,0.f,0.f}; acc3[m][n]=f32x4{0.f,0.f,0.f,0.f}; }

  gld_lds16(gA,  &lA [0][ldso]);
  gld_lds16(gB1, &lB1[0][ldso]);
  gld_lds16(gB3, &lB3[0][ldso]);
  __syncthreads();

  const int NK = DIM/BK;                 // 32
  int buf=0;
  for(int kt=0; kt<NK; kt++){
    if(kt+1<NK){
      gld_lds16(gA  + (kt+1)*BK, &lA [buf^1][ldso]);
      gld_lds16(gB1 + (kt+1)*BK, &lB1[buf^1][ldso]);
      gld_lds16(gB3 + (kt+1)*BK, &lB3[buf^1][ldso]);
    }
    bf16x8 av[4], bv[2], cv[2];
#pragma unroll
    for(int m=0;m<4;m++) av[m]=*reinterpret_cast<const bf16x8*>(&lA[buf][SWZ(wm*64+m*16+fr, gq)]);
#pragma unroll
    for(int n=0;n<2;n++){
      bv[n]=*reinterpret_cast<const bf16x8*>(&lB1[buf][SWZ(wn*32+n*16+fr, gq)]);
      cv[n]=*reinterpret_cast<const bf16x8*>(&lB3[buf][SWZ(wn*32+n*16+fr, gq)]);
    }
#pragma unroll
    for(int m=0;m<4;m++)
#pragma unroll
      for(int n=0;n<2;n++){
        acc1[m][n]=MFMA(av[m],bv[n],acc1[m][n]);
        acc3[m][n]=MFMA(av[m],cv[n],acc3[m][n]);
      }
    __syncthreads();
    buf^=1;
  }

#pragma unroll
  for(int m=0;m<4;m++){
    int rbase = row0 + wm*64 + m*16 + (gq<<2);
#pragma unroll
    for(int r=0;r<4;r++){
      if(rbase+r < row_end){
        __bf16* hp = h + (size_t)(rbase+r)*HID + n0 + wn*32 + fr;
#pragma unroll
        for(int n=0;n<2;n++){
          float u = acc1[m][n][r], v = acc3[m][n][r];
          hp[n*16] = (__bf16)( (u/(1.f+__expf(-u))) * v );
        }
      }
    }
  }
}

// ======== FFN2: ys = h @ w2^T — 128x256 tile, wave 64x64, ffn1-matched density ========
__global__ __launch_bounds__(512) void k_ffn2(
    const __bf16* __restrict__ h, const __bf16* __restrict__ w2b,
    const int* __restrict__ off, const int* __restrict__ mtp,
    __bf16* __restrict__ ys)
{
  __shared__ __align__(16) __bf16 lA[2][128*BK];    // 16 KB
  __shared__ __align__(16) __bf16 lB[2][256*BK];    // 32 KB

  const int NT = DIM/256;                // 4
  int wg = xcd_map(blockIdx.x, MAXMT*NT);
  int mt = wg / NT, nt = wg % NT;
  if (mt >= mtp[NE]) return;
  int e = 0;
  while (mt >= mtp[e+1]) e++;
  int row0    = off[e] + (mt - mtp[e])*BM;
  int row_end = off[e+1];
  int n0      = nt*256;

  int tid = threadIdx.x, lane = tid&63;
  int srow = tid>>2;
  int scol = ((tid&3) ^ ((srow>>1)&3))<<3;
  int s2col = ((tid&3) ^ (((srow+128)>>1)&3))<<3;    // swizzle for B rows 128..255
  int hrow = min(row0 + srow, NSLOT-1);
  const __bf16* gA  = h   + (size_t)hrow*HID + scol;
  const __bf16* gB0 = w2b + (size_t)e*DIM*HID + (size_t)(n0+srow)*HID + scol;
  const __bf16* gB1 = w2b + (size_t)e*DIM*HID + (size_t)(n0+srow+128)*HID + s2col;
  int ldso = (tid>>6)<<9;

  int wm = (tid>>6)>>2, wn = (tid>>6)&3; // 2x4 waves; wave tile 64(M)x64(N)
  int fr = lane & 15, gq = lane>>4;

  f32x4 acc[4][4];
#pragma unroll
  for(int m=0;m<4;m++)
#pragma unroll
    for(int n=0;n<4;n++) acc[m][n]=f32x4{0.f,0.f,0.f,0.f};

  gld_lds16(gA,  &lA[0][ldso]);
  gld_lds16(gB0, &lB[0][ldso]);
  gld_lds16(gB1, &lB[0][4096+ldso]);
  __syncthreads();

  const int NK = HID/BK;                 // 88
  int buf=0;
  for(int kt=0; kt<NK; kt++){
    if(kt+1<NK){
      gld_lds16(gA  + (kt+1)*BK, &lA[buf^1][ldso]);
      gld_lds16(gB0 + (kt+1)*BK, &lB[buf^1][ldso]);
      gld_lds16(gB1 + (kt+1)*BK, &lB[buf^1][4096+ldso]);
    }
    bf16x8 av[4], bv[4];
#pragma unroll
    for(int m=0;m<4;m++) av[m]=*reinterpret_cast<const bf16x8*>(&lA[buf][SWZ(wm*64+m*16+fr, gq)]);
#pragma unroll
    for(int n=0;n<4;n++) bv[n]=*reinterpret_cast<const bf16x8*>(&lB[buf][SWZ(wn*64+n*16+fr, gq)]);
#pragma unroll
    for(int m=0;m<4;m++)
#pragma unroll
      for(int n=0;n<4;n++)
        acc[m][n]=MFMA(av[m],bv[n],acc[m][n]);
    __syncthreads();
    buf^=1;
  }

  // epilogue: per-slot bf16 ys (no atomics)
#pragma unroll
  for(int m=0;m<4;m++){
    int rbase = row0 + wm*64 + m*16 + (gq<<2);
#pragma unroll
    for(int r=0;r<4;r++){
      if(rbase+r < row_end){
        __bf16* yp = ys + (size_t)(rbase+r)*DIM + n0 + wn*64 + fr;
#pragma unroll
        for(int n=0;n<4;n++) yp[n*16] = (__bf16)acc[m][n][r];
      }
    }
  }
}

// ---------------- weighted combine ----------------
__global__ __launch_bounds__(256) void k_combine(
    const __bf16* __restrict__ ys, const int* __restrict__ inv,
    const float* __restrict__ wt, float* __restrict__ y)
{
  int t  = blockIdx.x;
  int p0 = inv[2*t], p1 = inv[2*t+1];
  float w0 = wt[2*t], w1v = wt[2*t+1];
  int d = threadIdx.x*4;
  const __bf16* r0 = ys + (size_t)p0*DIM + d;
  const __bf16* r1 = ys + (size_t)p1*DIM + d;
  f32x4 o;
#pragma unroll
  for(int j=0;j<4;j++) o[j] = w0*(float)r0[j] + w1v*(float)r1[j];
  *reinterpret_cast<f32x4*>(y + (size_t)t*DIM + d) = o;
}

// ---------------- launch ----------------
extern "C" void kernel_launch(void* const* d_in, const int* in_sizes, int n_in,
                              void* d_out, int out_size, void* d_ws, size_t ws_size,
                              hipStream_t stream)
{
  const float* x  = (const float*)d_in[0];
  const float* gw = (const float*)d_in[1];
  const float* w1 = (const float*)d_in[2];
  const float* w3 = (const float*)d_in[3];
  const float* w2 = (const float*)d_in[4];
  float* y = (float*)d_out;
  char* ws = (char*)d_ws;

  int*   cnt    = (int*)(ws + 0);
  int*   off    = (int*)(ws + 64);
  int*   mtp    = (int*)(ws + 128);
  int*   cursor = (int*)(ws + 256);
  int*   idxs   = (int*)(ws + 320);
  float* wt     = (float*)(ws + 320 + 65536);
  int*   order  = (int*)(ws + 320 + 2*65536);
  int*   inv    = (int*)(ws + 320 + 3*65536);
  __bf16* h     = (__bf16*)(ws + 262464);
  __bf16* xb    = (__bf16*)(ws + 262464 + 92274688ull);
  __bf16* w1b   = (__bf16*)(ws + 262464 + 92274688ull + 16777216ull);
  __bf16* w3b   = (__bf16*)(ws + 262464 + 92274688ull + 16777216ull + 46137344ull);
  __bf16* w2b   = (__bf16*)(ws + 262464 + 92274688ull + 16777216ull + 2*46137344ull);
  __bf16* ysb   = w1b;   // dead after k_ffn1 -> reuse (33.5MB <= 46MB)

  const int PB = (NE*HID*DIM/8)/256;     // 11264 blocks per tensor

  k_zero   <<<1, 64, 0, stream>>>(cnt);
  k_gate   <<<NTOK/4, 256, 0, stream>>>(x, gw, idxs, wt, cnt, xb);
  k_prep   <<<1, 64, 0, stream>>>(cnt, off, mtp, cursor);
  k_scatter<<<NTOK/256, 256, 0, stream>>>(idxs, cursor, order, inv);
  k_cvt3   <<<3*PB, 256, 0, stream>>>(w1, w3, w2, w1b, w3b, w2b);
  k_ffn1   <<<MAXMT*(HID/128), 512, 0, stream>>>(xb, w1b, w3b, off, mtp, order, h);
  k_ffn2   <<<MAXMT*(DIM/256), 512, 0, stream>>>(h, w2b, off, mtp, ysb);
  k_combine<<<NTOK, 256, 0, stream>>>(ysb, inv, wt, y);
}